// Round 3
// baseline (260.148 us; speedup 1.0000x reference)
//
#include <hip/hip_runtime.h>

// Shapes fixed by the reference: B=8, C=128, H=W=64 -> S=4096. All I/O fp32.
#define BB 8
#define CC 128
#define SS 4096
#define KT 64             // kv tile per iteration
#define NSPLIT 2          // KV split factor (flash-style partial softmax)
#define HKV (SS / NSPLIT) // kv tokens per block = 2048
#define SCALE 0.015625f   // 1/sqrt(H*W) = 1/64

typedef __attribute__((ext_vector_type(8))) short sh8;   // 8 bf16 (MFMA A/B frag)
typedef __attribute__((ext_vector_type(4))) float f32x4; // MFMA C/D frag

__device__ __forceinline__ float b2f(unsigned short u) {
    union { unsigned int i; float f; } x; x.i = ((unsigned int)u) << 16; return x.f;
}
__device__ __forceinline__ unsigned short f2b(float f) {  // RNE (used in cvt)
    union { float f; unsigned int i; } x; x.f = f;
    unsigned int r = x.i + 0x7fff + ((x.i >> 16) & 1);
    return (unsigned short)(r >> 16);
}
__device__ __forceinline__ unsigned short rhu(float f) {  // round-half-up, 2 VALU
    union { float f; unsigned int i; } x; x.f = f;
    return (unsigned short)((x.i + 0x8000) >> 16);
}
// pack 2 f32 -> 2 bf16 in one dword (lo = first arg). No builtin on gfx950.
__device__ __forceinline__ unsigned int cvtpk(float lo, float hi) {
    unsigned int r;
    asm("v_cvt_pk_bf16_f32 %0, %1, %2" : "=v"(r) : "v"(lo), "v"(hi));
    return r;
}

// async 16B global->LDS DMA (lane i writes lds_base + i*16; LDS base wave-uniform)
__device__ __forceinline__ void dma16(const void* g, void* l) {
    __builtin_amdgcn_global_load_lds((const __attribute__((address_space(1))) void*)g,
                                     (__attribute__((address_space(3))) void*)l,
                                     16, 0, 0);
}

// ---------------------------------------------------------------------------
// cvt: V fp32->bf16 (layout preserved) + W/bias fp32->bf16 (one-time).
// blocks 0..511: V. blocks 512..519: Wq|Wk|bq|bk concat (33024 elems).
// ---------------------------------------------------------------------------
__global__ __launch_bounds__(256) void cvt_kernel(
    const float* __restrict__ vimg,
    const float* __restrict__ Wq, const float* __restrict__ Wk,
    const float* __restrict__ bq, const float* __restrict__ bk,
    unsigned short* __restrict__ Vbuf,
    unsigned short* __restrict__ Wqb, unsigned short* __restrict__ Wkb,
    unsigned short* __restrict__ bqb, unsigned short* __restrict__ bkb)
{
    const int bx = blockIdx.x, tid = threadIdx.x;
    if (bx < 512) {
        const size_t base = (size_t)bx * 8192 + tid * 4;
        #pragma unroll
        for (int it = 0; it < 8; ++it) {
            const size_t i = base + (size_t)it * 1024;
            float4 v = *(const float4*)(vimg + i);
            ushort4 o;
            o.x = f2b(v.x); o.y = f2b(v.y); o.z = f2b(v.z); o.w = f2b(v.w);
            *(ushort4*)(Vbuf + i) = o;
        }
    } else {
        const int w = bx - 512;  // 0..7
        for (int e = w * 256 + tid; e < 33024; e += 2048) {
            float v; unsigned short* dst;
            if (e < 16384)      { v = Wq[e];         dst = Wqb + e; }
            else if (e < 32768) { v = Wk[e - 16384]; dst = Wkb + (e - 16384); }
            else if (e < 32896) { v = bq[e - 32768]; dst = bqb + (e - 32768); }
            else                { v = bk[e - 32896]; dst = bkb + (e - 32896); }
            *dst = f2b(v);
        }
    }
}

// ---------------------------------------------------------------------------
// Projection with LDS-transposed img staging (coalesced float4 global loads).
// outTok[b][s][o] = sum_c img[b][c][s] * W[o][c] + bias[o]
// grid=(64, 8, 2): z=0 -> Q, z=1 -> K.
// ---------------------------------------------------------------------------
__global__ __launch_bounds__(256) void proj_kernel(
    const float* __restrict__ qimg, const float* __restrict__ kimg,
    const unsigned short* __restrict__ Wqb, const unsigned short* __restrict__ Wkb,
    const unsigned short* __restrict__ bqb, const unsigned short* __restrict__ bkb,
    unsigned short* __restrict__ Qbuf, unsigned short* __restrict__ Kbuf)
{
    __shared__ float ilds[128 * 69];   // 128 chans x (64 tokens + 5 pad) = 35,328 B

    const int z = blockIdx.z;
    const float* img = (z == 0) ? qimg : kimg;
    const unsigned short* Wb = (z == 0) ? Wqb : Wkb;
    const unsigned short* bias = (z == 0) ? bqb : bkb;
    unsigned short* outTok = (z == 0) ? Qbuf : Kbuf;

    const int tid  = threadIdx.x;
    const int wave = tid >> 6;
    const int lane = tid & 63;
    const int l15  = lane & 15;
    const int quad = lane >> 4;
    const int b     = blockIdx.y;
    const int stile = blockIdx.x;

    // stage 128x64 fp32 tile, coalesced (64B contiguous per 16 lanes)
    const float* gbase = img + (size_t)b * CC * SS + stile * 64;
    #pragma unroll
    for (int i = 0; i < 8; ++i) {
        const int l = tid + 256 * i;          // 0..2047
        const int row = l >> 4, col = (l & 15) * 4;
        float4 v = *(const float4*)(gbase + (size_t)row * SS + col);
        float* d = ilds + row * 69 + col;
        d[0] = v.x; d[1] = v.y; d[2] = v.z; d[3] = v.w;
    }
    __syncthreads();

    // A-frags from LDS: A[m=l15][k=32kk+quad*8+j] = img[c=k][token]
    const int tcol = wave * 16 + l15;
    sh8 a[4];
    #pragma unroll
    for (int kk = 0; kk < 4; ++kk)
        #pragma unroll
        for (int j = 0; j < 8; ++j)
            a[kk][j] = (short)rhu(ilds[(32 * kk + quad * 8 + j) * 69 + tcol]);

    f32x4 acc[8];
    #pragma unroll
    for (int nt = 0; nt < 8; ++nt) acc[nt] = (f32x4){0.f, 0.f, 0.f, 0.f};

    #pragma unroll
    for (int nt = 0; nt < 8; ++nt) {
        const unsigned short* wp = Wb + (size_t)(16 * nt + l15) * CC + quad * 8;
        #pragma unroll
        for (int kk = 0; kk < 4; ++kk) {
            sh8 bf = *(const sh8*)(wp + 32 * kk);
            acc[nt] = __builtin_amdgcn_mfma_f32_16x16x32_bf16(a[kk], bf, acc[nt], 0, 0, 0);
        }
    }

    #pragma unroll
    for (int nt = 0; nt < 8; ++nt) {
        const int o = 16 * nt + l15;
        const float bv = b2f(bias[o]);
        #pragma unroll
        for (int r = 0; r < 4; ++r) {
            const int s = stile * 64 + wave * 16 + quad * 4 + r;
            outTok[((size_t)b * SS + s) * CC + o] = f2b(acc[nt][r] + bv);
        }
    }
}

// ---------------------------------------------------------------------------
// Flash attention v3: LDS-minimal.
//   - swapped QK^T (mfma(K,Q)) with PERMUTED K-row mapping so each lane's
//     score registers are exactly its PV A-operand k-slots -> softmax and
//     P stay fully in-register (cvt_pk only, no LDS P, no cross-lane ops).
//     row'(n,i) = 32(n>>1) + 8(i>>2) + 4(n&1) + (i&3): lane (l15,q) reg r of
//     frag n holds token 32(n>>1)+8q+4(n&1)+r = k-slot q*8+(4(n&1)+r) of
//     PV chunk kp=n>>1.  (exp/sum are permutation-invariant.)
//   - V frags read straight from global (16B/lane, quads cover 64B lines;
//     XCD-local L2 via b=wgid&7, L1-reused by the block's 4 waves) ->
//     V never touches LDS.
//   - LDS = K double-buffer only (32 KB), swizzle s(row)=(row&3)|((row>>1)&4)
//     (keeps permuted reads at the free 2-way bank level). 1 barrier/iter.
// Block: 4 waves x 32 q = 128 q over HKV=2048 kv; grid 512 = 2 blocks/CU.
// LDS 34,816 B (K dbuf 32 KB; epilogue oT ushort[128][136] aliases it).
// Output: UNNORMALIZED O (bf16) + row-sums L (f32); combine_kernel merges.
// ---------------------------------------------------------------------------
__global__ __launch_bounds__(256, 2) void attn_kernel(
    const unsigned short* __restrict__ Qbuf,  // (B,S,C) bf16 token-major
    const unsigned short* __restrict__ Kbuf,  // (B,S,C) bf16 token-major
    const unsigned short* __restrict__ Vbuf,  // (B,C,S) bf16 channel-major
    unsigned short* __restrict__ Opart,       // (NSPLIT,B,C,S) bf16 partial O
    float* __restrict__ Lsum)                 // (NSPLIT,B,S) f32 partial sums
{
    __shared__ __align__(16) unsigned char smem[34816];

    const int tid  = threadIdx.x;
    const int wave = tid >> 6;
    const int lane = tid & 63;
    const int l15  = lane & 15;
    const int quad = lane >> 4;
    const int wgid = blockIdx.x;
    const int b    = wgid & 7;          // batch == XCD (L2 holds one batch's K/V)
    const int half = (wgid >> 3) & 1;   // KV half
    const int qt   = wgid >> 4;         // 0..31, 128 queries each
    const int qbase = qt * 128 + wave * 32;
    const int tok0  = half * HKV;

    const unsigned short* kbp = Kbuf + (size_t)b * SS * CC;
    const unsigned short* vbp = Vbuf + (size_t)b * CC * SS;

    // Q frags (B operand of swapped QK; same per-lane layout as before)
    sh8 aq[2][4];
    #pragma unroll
    for (int m = 0; m < 2; ++m) {
        const unsigned short* qp = Qbuf + ((size_t)b * SS + qbase + m * 16 + l15) * CC + quad * 8;
        #pragma unroll
        for (int kk = 0; kk < 4; ++kk) aq[m][kk] = *(const sh8*)(qp + 32 * kk);
    }

    // K DMA source offsets (bytes); swizzle s(row) = (row&3)|((row>>1)&4)
    int kGO[4];
    #pragma unroll
    for (int j = 0; j < 4; ++j) {
        const int krow = wave * 16 + j * 4 + quad;
        const int sx = (krow & 3) | ((krow >> 1) & 4);
        kGO[j] = krow * 256 + (((lane & 15) ^ sx) << 4);
    }

    // K read addressing: permuted row per frag n (depends on l15 only)
    int krb[4], krs[4];
    #pragma unroll
    for (int n = 0; n < 4; ++n) {
        const int rowp = 32 * (n >> 1) + 8 * (l15 >> 2) + 4 * (n & 1) + (l15 & 3);
        krb[n] = rowp * 256;
        krs[n] = (rowp & 3) | ((rowp >> 1) & 4);
    }

    // V per-lane base: chan = 16ct + l15, tokens 8*quad.. (16B contiguous)
    const unsigned short* vlane = vbp + (size_t)l15 * SS + quad * 8 + tok0;

    f32x4 oacc[2][8];
    #pragma unroll
    for (int m = 0; m < 2; ++m)
        #pragma unroll
        for (int ct = 0; ct < 8; ++ct) oacc[m][ct] = (f32x4){0.f, 0.f, 0.f, 0.f};
    float lsum[2] = {0.f, 0.f};

    // prologue: stage K[0] -> buf0
    const char* gk0 = (const char*)kbp + (size_t)tok0 * 256;
    #pragma unroll
    for (int j = 0; j < 4; ++j)
        dma16(gk0 + kGO[j], smem + (wave * 4 + j) * 1024);

    for (int it = 0; it < HKV / KT; ++it) {
        unsigned char* kb = smem + ((it & 1) << 14);

        __syncthreads();   // K[it] resident (own DMA drained) + buf^1 free

        // K double-buffer: issue next tile now; lands by next barrier
        if (it + 1 < HKV / KT) {
            const char* gk = gk0 + (size_t)(it + 1) * KT * 256;
            unsigned char* kbn = smem + (((it + 1) & 1) << 14);
            #pragma unroll
            for (int j = 0; j < 4; ++j) dma16(gk + kGO[j], kbn + (wave * 4 + j) * 1024);
        }

        // V frags chunk kp=0 from global (latency covered by QK)
        const unsigned short* vit = vlane + it * KT;
        sh8 vv0[8], vv1[8];
        #pragma unroll
        for (int ct = 0; ct < 8; ++ct)
            vv0[ct] = *(const sh8*)(vit + (size_t)ct * 16 * SS);

        // --- S^T = K Q^T with permuted K rows ---
        f32x4 sacc[2][4];
        #pragma unroll
        for (int m = 0; m < 2; ++m)
            #pragma unroll
            for (int n = 0; n < 4; ++n) sacc[m][n] = (f32x4){0.f, 0.f, 0.f, 0.f};
        __builtin_amdgcn_s_setprio(1);
        #pragma unroll
        for (int n = 0; n < 4; ++n) {
            #pragma unroll
            for (int kk = 0; kk < 4; ++kk) {
                sh8 kf = *(const sh8*)(kb + krb[n] + (((4 * kk + quad) ^ krs[n]) << 4));
                sacc[0][n] = __builtin_amdgcn_mfma_f32_16x16x32_bf16(kf, aq[0][kk], sacc[0][n], 0, 0, 0);
                sacc[1][n] = __builtin_amdgcn_mfma_f32_16x16x32_bf16(kf, aq[1][kk], sacc[1][n], 0, 0, 0);
            }
        }
        __builtin_amdgcn_s_setprio(0);

        // V frags chunk kp=1 (latency covered by softmax + PV kp=0)
        #pragma unroll
        for (int ct = 0; ct < 8; ++ct)
            vv1[ct] = *(const sh8*)(vit + (size_t)ct * 16 * SS + 32);

        // --- softmax fully in-register: exp, accumulate, pack to PV A-frags ---
        union { sh8 v; unsigned int d[4]; } pa[2][2];
        #pragma unroll
        for (int m = 0; m < 2; ++m) {
            float p[4][4];
            #pragma unroll
            for (int n = 0; n < 4; ++n)
                #pragma unroll
                for (int r = 0; r < 4; ++r) {
                    p[n][r] = __expf(sacc[m][n][r] * SCALE);
                    lsum[m] += p[n][r];
                }
            #pragma unroll
            for (int kp = 0; kp < 2; ++kp) {
                pa[m][kp].d[0] = cvtpk(p[2 * kp][0],     p[2 * kp][1]);
                pa[m][kp].d[1] = cvtpk(p[2 * kp][2],     p[2 * kp][3]);
                pa[m][kp].d[2] = cvtpk(p[2 * kp + 1][0], p[2 * kp + 1][1]);
                pa[m][kp].d[3] = cvtpk(p[2 * kp + 1][2], p[2 * kp + 1][3]);
            }
        }

        // --- PV: V from registers, P from registers ---
        __builtin_amdgcn_s_setprio(1);
        #pragma unroll
        for (int ct = 0; ct < 8; ++ct) {
            oacc[0][ct] = __builtin_amdgcn_mfma_f32_16x16x32_bf16(pa[0][0].v, vv0[ct], oacc[0][ct], 0, 0, 0);
            oacc[1][ct] = __builtin_amdgcn_mfma_f32_16x16x32_bf16(pa[1][0].v, vv0[ct], oacc[1][ct], 0, 0, 0);
        }
        #pragma unroll
        for (int ct = 0; ct < 8; ++ct) {
            oacc[0][ct] = __builtin_amdgcn_mfma_f32_16x16x32_bf16(pa[0][1].v, vv1[ct], oacc[0][ct], 0, 0, 0);
            oacc[1][ct] = __builtin_amdgcn_mfma_f32_16x16x32_bf16(pa[1][1].v, vv1[ct], oacc[1][ct], 0, 0, 0);
        }
        __builtin_amdgcn_s_setprio(0);
    }

    // --- total row-sum: add across the 4 quads holding the same query ---
    #pragma unroll
    for (int m = 0; m < 2; ++m) {
        lsum[m] += __shfl_xor(lsum[m], 16, 64);
        lsum[m] += __shfl_xor(lsum[m], 32, 64);
    }
    if (quad == 0) {
        float* lp = Lsum + ((size_t)half * BB + b) * SS + qbase;
        lp[l15]      = lsum[0];
        lp[16 + l15] = lsum[1];
    }

    __syncthreads();   // all K-buffer reads done before aliasing smem

    // --- epilogue: unnormalized O -> bf16, LDS transpose, coalesced store ---
    unsigned short* oT = (unsigned short*)smem;   // [128 c][136 pad] ushorts
    #pragma unroll
    for (int m = 0; m < 2; ++m)
        #pragma unroll
        for (int ct = 0; ct < 8; ++ct) {
            const int c  = 16 * ct + l15;
            const int q0 = wave * 32 + m * 16 + quad * 4;
            ushort4 o;
            o.x = rhu(oacc[m][ct][0]); o.y = rhu(oacc[m][ct][1]);
            o.z = rhu(oacc[m][ct][2]); o.w = rhu(oacc[m][ct][3]);
            *(ushort4*)(oT + c * 136 + q0) = o;
        }
    __syncthreads();

    unsigned short* op = Opart + ((size_t)half * BB + b) * CC * SS + qt * 128;
    #pragma unroll
    for (int i = 0; i < 16; ++i) {
        const int idx = tid + 256 * i;        // 0..4095
        const int c = idx >> 5, q4 = (idx & 31) * 4;
        *(ushort4*)(op + (size_t)c * SS + q4) = *(const ushort4*)(oT + c * 136 + q4);
    }
}

// ---------------------------------------------------------------------------
// combine: out[b][c][s] = (O0+O1)/(L0+L1) + resid(Qbuf[b][s][c]).
// grid (64,8), 256 thr. Lanes span s (coalesced fp32 stores); resid reads are
// 2B stride-256B but L1-resident (16 KB row footprint, reused across c).
// ---------------------------------------------------------------------------
__global__ __launch_bounds__(256) void combine_kernel(
    const unsigned short* __restrict__ Qbuf,
    const unsigned short* __restrict__ Opart,
    const float* __restrict__ Lsum,
    float* __restrict__ out)
{
    const int b = blockIdx.y, st = blockIdx.x, tid = threadIdx.x;
    const int s0   = st * 64 + (tid & 15) * 4;   // 4 consecutive tokens
    const int coff = tid >> 4;                   // 16 channel phases

    float4 l0 = *(const float4*)(Lsum + (size_t)b * SS + s0);
    float4 l1 = *(const float4*)(Lsum + ((size_t)BB + b) * SS + s0);
    float rinv[4];
    rinv[0] = 1.f / (l0.x + l1.x); rinv[1] = 1.f / (l0.y + l1.y);
    rinv[2] = 1.f / (l0.z + l1.z); rinv[3] = 1.f / (l0.w + l1.w);

    const unsigned short* qb = Qbuf + (size_t)b * SS * CC;
    for (int c = coff; c < CC; c += 16) {
        const size_t po = ((size_t)b * CC + c) * SS + s0;
        ushort4 p0 = *(const ushort4*)(Opart + po);
        ushort4 p1 = *(const ushort4*)(Opart + (size_t)BB * CC * SS + po);
        float4 o;
        o.x = (b2f(p0.x) + b2f(p1.x)) * rinv[0] + b2f(qb[(size_t)(s0 + 0) * CC + c]);
        o.y = (b2f(p0.y) + b2f(p1.y)) * rinv[1] + b2f(qb[(size_t)(s0 + 1) * CC + c]);
        o.z = (b2f(p0.z) + b2f(p1.z)) * rinv[2] + b2f(qb[(size_t)(s0 + 2) * CC + c]);
        o.w = (b2f(p0.w) + b2f(p1.w)) * rinv[3] + b2f(qb[(size_t)(s0 + 3) * CC + c]);
        *(float4*)(out + po) = o;
    }
}

extern "C" void kernel_launch(void* const* d_in, const int* in_sizes, int n_in,
                              void* d_out, int out_size, void* d_ws, size_t ws_size,
                              hipStream_t stream) {
    const float* qimg = (const float*)d_in[0];
    const float* kimg = (const float*)d_in[1];
    const float* vimg = (const float*)d_in[2];
    const float* Wq   = (const float*)d_in[3];
    const float* bq   = (const float*)d_in[4];
    const float* Wk   = (const float*)d_in[5];
    const float* bk   = (const float*)d_in[6];
    float* out = (float*)d_out;

    // workspace map (needs ~42.3 MB):
    unsigned short* Qbuf = (unsigned short*)d_ws;                    // 8 MB
    unsigned short* Kbuf = Qbuf + (size_t)BB * SS * CC;              // 8 MB
    unsigned short* Vbuf = Kbuf + (size_t)BB * SS * CC;              // 8 MB
    unsigned short* Wqb  = Vbuf + (size_t)BB * SS * CC;              // 32 KB
    unsigned short* Wkb  = Wqb + CC * CC;                            // 32 KB
    unsigned short* bqb  = Wkb + CC * CC;
    unsigned short* bkb  = bqb + CC;
    unsigned short* Opart = bkb + CC;                                // 16 MB bf16
    float* Lsum = (float*)(Opart + (size_t)NSPLIT * BB * CC * SS);   // 256 KB

    cvt_kernel<<<dim3(520), 256, 0, stream>>>(vimg, Wq, Wk, bq, bk,
                                              Vbuf, Wqb, Wkb, bqb, bkb);
    proj_kernel<<<dim3(SS / 64, BB, 2), 256, 0, stream>>>(
        qimg, kimg, Wqb, Wkb, bqb, bkb, Qbuf, Kbuf);
    attn_kernel<<<dim3(NSPLIT * BB * (SS / 128)), 256, 0, stream>>>(
        Qbuf, Kbuf, Vbuf, Opart, Lsum);
    combine_kernel<<<dim3(SS / 64, BB), 256, 0, stream>>>(Qbuf, Opart, Lsum, out);
}

// Round 5
// 209.655 us; speedup vs baseline: 1.2408x; 1.2408x over previous
//
#include <hip/hip_runtime.h>

// Shapes fixed by the reference: B=8, C=128, H=W=64 -> S=4096. All I/O fp32.
#define BB 8
#define CC 128
#define SS 4096
#define KT 64             // kv tile per iteration
#define NSPLIT 2          // KV split factor (flash-style partial softmax)
#define HKV (SS / NSPLIT) // kv tokens per block = 2048
#define SCALE 0.015625f   // 1/sqrt(H*W) = 1/64

typedef __attribute__((ext_vector_type(8))) short sh8;   // 8 bf16 (MFMA A/B frag)
typedef __attribute__((ext_vector_type(4))) float f32x4; // MFMA C/D frag

__device__ __forceinline__ float b2f(unsigned short u) {
    union { unsigned int i; float f; } x; x.i = ((unsigned int)u) << 16; return x.f;
}
__device__ __forceinline__ unsigned short f2b(float f) {  // RNE
    union { float f; unsigned int i; } x; x.f = f;
    unsigned int r = x.i + 0x7fff + ((x.i >> 16) & 1);
    return (unsigned short)(r >> 16);
}
__device__ __forceinline__ unsigned short rhu(float f) {  // round-half-up, 2 VALU
    union { float f; unsigned int i; } x; x.f = f;
    return (unsigned short)((x.i + 0x8000) >> 16);
}
// pack 2 f32 -> 2 bf16 in one dword (lo = first arg). No builtin on gfx950.
__device__ __forceinline__ unsigned int cvtpk(float lo, float hi) {
    unsigned int r;
    asm("v_cvt_pk_bf16_f32 %0, %1, %2" : "=v"(r) : "v"(lo), "v"(hi));
    return r;
}

// async 16B global->LDS DMA (lane i writes lds_base + i*16; LDS base wave-uniform)
__device__ __forceinline__ void dma16(const void* g, void* l) {
    __builtin_amdgcn_global_load_lds((const __attribute__((address_space(1))) void*)g,
                                     (__attribute__((address_space(3))) void*)l,
                                     16, 0, 0);
}

// ---------------------------------------------------------------------------
// proj (fused): z=0 -> Q proj, z=1 -> K proj, z=2 -> V fp32->bf16 copy.
// Weights are converted inline from fp32 (v_cvt_pk_bf16_f32, RNE — same
// rounding as the old cvt pass); bias is applied in full fp32.
// outTok[b][s][o] = sum_c img[b][c][s] * W[o][c] + bias[o]
// grid=(64, 8, 3), 256 threads.
// ---------------------------------------------------------------------------
__global__ __launch_bounds__(256) void proj_kernel(
    const float* __restrict__ qimg, const float* __restrict__ kimg,
    const float* __restrict__ vimg,
    const float* __restrict__ Wq, const float* __restrict__ Wk,
    const float* __restrict__ bq, const float* __restrict__ bk,
    unsigned short* __restrict__ Qbuf, unsigned short* __restrict__ Kbuf,
    unsigned short* __restrict__ Vbuf)
{
    __shared__ float ilds[128 * 69];   // 128 chans x (64 tokens + 5 pad) = 35,328 B

    const int z = blockIdx.z;
    const int b     = blockIdx.y;
    const int stile = blockIdx.x;
    const int tid   = threadIdx.x;

    if (z == 2) {   // V conversion: 64-token x 128-chan tile, coalesced float4
        const float* src = vimg + (size_t)b * CC * SS + stile * 64;
        unsigned short* dst = Vbuf + (size_t)b * CC * SS + stile * 64;
        #pragma unroll
        for (int i = 0; i < 8; ++i) {
            const int idx = tid + i * 256;        // 0..2047
            const int c = idx >> 4, t4 = (idx & 15) * 4;
            float4 v = *(const float4*)(src + (size_t)c * SS + t4);
            ushort4 o;
            o.x = f2b(v.x); o.y = f2b(v.y); o.z = f2b(v.z); o.w = f2b(v.w);
            *(ushort4*)(dst + (size_t)c * SS + t4) = o;
        }
        return;
    }

    const float* img  = (z == 0) ? qimg : kimg;
    const float* Wf   = (z == 0) ? Wq : Wk;
    const float* bias = (z == 0) ? bq : bk;
    unsigned short* outTok = (z == 0) ? Qbuf : Kbuf;

    const int wave = tid >> 6;
    const int lane = tid & 63;
    const int l15  = lane & 15;
    const int quad = lane >> 4;

    // stage 128x64 fp32 tile, coalesced (64B contiguous per 16 lanes)
    const float* gbase = img + (size_t)b * CC * SS + stile * 64;
    #pragma unroll
    for (int i = 0; i < 8; ++i) {
        const int l = tid + 256 * i;          // 0..2047
        const int row = l >> 4, col = (l & 15) * 4;
        float4 v = *(const float4*)(gbase + (size_t)row * SS + col);
        float* d = ilds + row * 69 + col;
        d[0] = v.x; d[1] = v.y; d[2] = v.z; d[3] = v.w;
    }
    __syncthreads();

    // A-frags from LDS: A[m=l15][k=32kk+quad*8+j] = img[c=k][token]
    const int tcol = wave * 16 + l15;
    sh8 a[4];
    #pragma unroll
    for (int kk = 0; kk < 4; ++kk)
        #pragma unroll
        for (int j = 0; j < 8; ++j)
            a[kk][j] = (short)rhu(ilds[(32 * kk + quad * 8 + j) * 69 + tcol]);

    f32x4 acc[8];
    #pragma unroll
    for (int nt = 0; nt < 8; ++nt) acc[nt] = (f32x4){0.f, 0.f, 0.f, 0.f};

    #pragma unroll
    for (int nt = 0; nt < 8; ++nt) {
        const float* wp = Wf + (size_t)(16 * nt + l15) * CC + quad * 8;
        #pragma unroll
        for (int kk = 0; kk < 4; ++kk) {
            float4 w0 = *(const float4*)(wp + 32 * kk);
            float4 w1 = *(const float4*)(wp + 32 * kk + 4);
            union { sh8 v; unsigned int d[4]; } bf;
            bf.d[0] = cvtpk(w0.x, w0.y); bf.d[1] = cvtpk(w0.z, w0.w);
            bf.d[2] = cvtpk(w1.x, w1.y); bf.d[3] = cvtpk(w1.z, w1.w);
            acc[nt] = __builtin_amdgcn_mfma_f32_16x16x32_bf16(a[kk], bf.v, acc[nt], 0, 0, 0);
        }
    }

    #pragma unroll
    for (int nt = 0; nt < 8; ++nt) {
        const int o = 16 * nt + l15;
        const float bv = bias[o];
        #pragma unroll
        for (int r = 0; r < 4; ++r) {
            const int s = stile * 64 + wave * 16 + quad * 4 + r;
            outTok[((size_t)b * SS + s) * CC + o] = f2b(acc[nt][r] + bv);
        }
    }
}

// ---------------------------------------------------------------------------
// Flash attention v4 = round-2 V transport + round-3 in-register P.
//   - swapped QK^T (mfma(K,Q)) with PERMUTED K-row mapping: lane (quad,l15)
//     reg r of frag n holds S[token 32(n>>1)+8*quad+4(n&1)+r][query l15] --
//     exactly the PV A-operand k-slots, so softmax/P stay fully in-register
//     (cvt_pk only; no LDS P, no cross-lane ops).
//   - K and V both DMA'd global->LDS one tile ahead, DOUBLE-buffered ->
//     exactly one __syncthreads per iteration (its vmcnt(0) drains own DMAs;
//     its lgkmcnt(0) retires prev-iter LDS reads before buffer overwrite).
// Block: 4 waves x 32 q = 128 q over HKV=2048 kv; grid 512 = 2 blocks/CU.
// LDS 65,536 B: K dbuf 2x16 KB [0,32768), V dbuf 2x16 KB [32768,65536).
//   K rows 64 x 256 B, chunk swizzle ^((r&3)|((r>>1)&4)); read-side term
//   reduces to ^(l15&7) for the permuted rows (verified algebraically).
//   V rows 128 chans x 128 B, chunk swizzle ^(row&7).
//   epilogue: oT ushort[128][136] (34,816 B) aliases front after barrier.
// Output: UNNORMALIZED O (bf16) + row-sums L (f32); combine_kernel merges.
// ---------------------------------------------------------------------------
__global__ __launch_bounds__(256, 2) void attn_kernel(
    const unsigned short* __restrict__ Qbuf,  // (B,S,C) bf16 token-major
    const unsigned short* __restrict__ Kbuf,  // (B,S,C) bf16 token-major
    const unsigned short* __restrict__ Vbuf,  // (B,C,S) bf16 channel-major
    unsigned short* __restrict__ Opart,       // (NSPLIT,B,C,S) bf16 partial O
    float* __restrict__ Lsum)                 // (NSPLIT,B,S) f32 partial sums
{
    __shared__ __align__(16) unsigned char smem[65536];

    const int tid  = threadIdx.x;
    const int wave = tid >> 6;
    const int lane = tid & 63;
    const int l15  = lane & 15;
    const int quad = lane >> 4;
    const int wgid = blockIdx.x;
    const int b    = wgid & 7;          // batch == XCD (L2 holds one batch's K/V)
    const int half = (wgid >> 3) & 1;   // KV half
    const int qt   = wgid >> 4;         // 0..31, 128 queries each
    const int qbase = qt * 128 + wave * 32;
    const int tok0  = half * HKV;

    const unsigned short* kbp = Kbuf + (size_t)b * SS * CC;
    const unsigned short* vbp = Vbuf + (size_t)b * CC * SS;

    // Q frags (B operand of swapped QK)
    sh8 aq[2][4];
    #pragma unroll
    for (int m = 0; m < 2; ++m) {
        const unsigned short* qp = Qbuf + ((size_t)b * SS + qbase + m * 16 + l15) * CC + quad * 8;
        #pragma unroll
        for (int kk = 0; kk < 4; ++kk) aq[m][kk] = *(const sh8*)(qp + 32 * kk);
    }

    // DMA source offsets (bytes), constant across iterations
    int kGO[4], vGO[4];
    #pragma unroll
    for (int j = 0; j < 4; ++j) {
        const int krow = wave * 16 + j * 4 + quad;
        const int sx = (krow & 3) | ((krow >> 1) & 4);
        kGO[j] = krow * 256 + (((lane & 15) ^ sx) << 4);
        const int vrow = (wave * 4 + j) * 8 + (lane >> 3);
        vGO[j] = vrow * 8192 + (((lane & 7) ^ ((lane >> 3) & 7)) << 4);
    }

    // K read addressing: permuted row per frag n; swizzle term == l15&7 for all n
    int krb[4];
    #pragma unroll
    for (int n = 0; n < 4; ++n)
        krb[n] = (32 * (n >> 1) + 8 * (l15 >> 2) + 4 * (n & 1) + (l15 & 3)) * 256;
    const int krs = l15 & 7;

    f32x4 oacc[2][8];
    #pragma unroll
    for (int m = 0; m < 2; ++m)
        #pragma unroll
        for (int ct = 0; ct < 8; ++ct) oacc[m][ct] = (f32x4){0.f, 0.f, 0.f, 0.f};
    float lsum[2] = {0.f, 0.f};

    const char* gk0 = (const char*)kbp + (size_t)tok0 * 256;
    const char* gv0 = (const char*)vbp + (size_t)tok0 * 2;

    // prologue: stage K[0], V[0] into buffer 0
    #pragma unroll
    for (int j = 0; j < 4; ++j) {
        dma16(gk0 + kGO[j], smem + (wave * 4 + j) * 1024);
        dma16(gv0 + vGO[j], smem + 32768 + (wave * 4 + j) * 1024);
    }

    for (int it = 0; it < HKV / KT; ++it) {
        unsigned char* kb = smem + ((it & 1) << 14);
        unsigned char* vb = smem + 32768 + ((it & 1) << 14);

        // one barrier/iter: drains own DMA (vmcnt) + own LDS reads (lgkm),
        // then syncs -> K[it],V[it] resident and other buffers reusable.
        __syncthreads();

        // issue next-tile DMA into the other buffers; lands by next barrier
        if (it + 1 < HKV / KT) {
            const char* gk = gk0 + (size_t)(it + 1) * KT * 256;
            const char* gv = gv0 + (size_t)(it + 1) * KT * 2;
            unsigned char* kbn = smem + (((it + 1) & 1) << 14);
            unsigned char* vbn = smem + 32768 + (((it + 1) & 1) << 14);
            #pragma unroll
            for (int j = 0; j < 4; ++j) {
                dma16(gk + kGO[j], kbn + (wave * 4 + j) * 1024);
                dma16(gv + vGO[j], vbn + (wave * 4 + j) * 1024);
            }
        }

        // --- S^T = K Q^T with permuted K rows ---
        f32x4 sacc[2][4];
        #pragma unroll
        for (int m = 0; m < 2; ++m)
            #pragma unroll
            for (int n = 0; n < 4; ++n) sacc[m][n] = (f32x4){0.f, 0.f, 0.f, 0.f};
        __builtin_amdgcn_s_setprio(1);
        #pragma unroll
        for (int n = 0; n < 4; ++n) {
            #pragma unroll
            for (int kk = 0; kk < 4; ++kk) {
                sh8 kf = *(const sh8*)(kb + krb[n] + (((4 * kk + quad) ^ krs) << 4));
                sacc[0][n] = __builtin_amdgcn_mfma_f32_16x16x32_bf16(kf, aq[0][kk], sacc[0][n], 0, 0, 0);
                sacc[1][n] = __builtin_amdgcn_mfma_f32_16x16x32_bf16(kf, aq[1][kk], sacc[1][n], 0, 0, 0);
            }
        }
        __builtin_amdgcn_s_setprio(0);

        // --- softmax fully in-register: exp, accumulate, pack to PV A-frags ---
        union { sh8 v; unsigned int d[4]; } pa[2][2];
        #pragma unroll
        for (int m = 0; m < 2; ++m) {
            float p[4][4];
            #pragma unroll
            for (int n = 0; n < 4; ++n)
                #pragma unroll
                for (int r = 0; r < 4; ++r) {
                    p[n][r] = __expf(sacc[m][n][r] * SCALE);
                    lsum[m] += p[n][r];
                }
            #pragma unroll
            for (int kp = 0; kp < 2; ++kp) {
                pa[m][kp].d[0] = cvtpk(p[2 * kp][0],     p[2 * kp][1]);
                pa[m][kp].d[1] = cvtpk(p[2 * kp][2],     p[2 * kp][3]);
                pa[m][kp].d[2] = cvtpk(p[2 * kp + 1][0], p[2 * kp + 1][1]);
                pa[m][kp].d[3] = cvtpk(p[2 * kp + 1][2], p[2 * kp + 1][3]);
            }
        }

        // --- PV: P from registers, V from LDS (8 frag reads per kp) ---
        __builtin_amdgcn_s_setprio(1);
        #pragma unroll
        for (int kp = 0; kp < 2; ++kp) {
            #pragma unroll
            for (int ct = 0; ct < 8; ++ct) {
                sh8 bv = *(const sh8*)(vb + (16 * ct + l15) * 128
                                          + (((kp * 4 + quad) ^ (l15 & 7)) << 4));
                oacc[0][ct] = __builtin_amdgcn_mfma_f32_16x16x32_bf16(pa[0][kp].v, bv, oacc[0][ct], 0, 0, 0);
                oacc[1][ct] = __builtin_amdgcn_mfma_f32_16x16x32_bf16(pa[1][kp].v, bv, oacc[1][ct], 0, 0, 0);
            }
        }
        __builtin_amdgcn_s_setprio(0);
    }

    // --- total row-sum: add across the 4 quads holding the same query ---
    #pragma unroll
    for (int m = 0; m < 2; ++m) {
        lsum[m] += __shfl_xor(lsum[m], 16, 64);
        lsum[m] += __shfl_xor(lsum[m], 32, 64);
    }
    if (quad == 0) {
        float* lp = Lsum + ((size_t)half * BB + b) * SS + qbase;
        lp[l15]      = lsum[0];
        lp[16 + l15] = lsum[1];
    }

    __syncthreads();   // all K/V-buffer reads done before aliasing smem

    // --- epilogue: unnormalized O -> bf16, LDS transpose, coalesced store ---
    unsigned short* oT = (unsigned short*)smem;   // [128 c][136 pad] ushorts
    #pragma unroll
    for (int m = 0; m < 2; ++m)
        #pragma unroll
        for (int ct = 0; ct < 8; ++ct) {
            const int c  = 16 * ct + l15;
            const int q0 = wave * 32 + m * 16 + quad * 4;
            ushort4 o;
            o.x = rhu(oacc[m][ct][0]); o.y = rhu(oacc[m][ct][1]);
            o.z = rhu(oacc[m][ct][2]); o.w = rhu(oacc[m][ct][3]);
            *(ushort4*)(oT + c * 136 + q0) = o;
        }
    __syncthreads();

    unsigned short* op = Opart + ((size_t)half * BB + b) * CC * SS + qt * 128;
    #pragma unroll
    for (int i = 0; i < 16; ++i) {
        const int idx = tid + 256 * i;        // 0..4095
        const int c = idx >> 5, q4 = (idx & 31) * 4;
        *(ushort4*)(op + (size_t)c * SS + q4) = *(const ushort4*)(oT + c * 136 + q4);
    }
}

// ---------------------------------------------------------------------------
// combine: out[b][c][s] = (O0+O1)/(L0+L1) + resid(Qbuf[b][s][c]).
// grid (64,8), 256 thr. Lanes span s (coalesced fp32 stores); resid reads are
// 2B stride-256B but L1-resident (16 KB row footprint, reused across c).
// ---------------------------------------------------------------------------
__global__ __launch_bounds__(256) void combine_kernel(
    const unsigned short* __restrict__ Qbuf,
    const unsigned short* __restrict__ Opart,
    const float* __restrict__ Lsum,
    float* __restrict__ out)
{
    const int b = blockIdx.y, st = blockIdx.x, tid = threadIdx.x;
    const int s0   = st * 64 + (tid & 15) * 4;   // 4 consecutive tokens
    const int coff = tid >> 4;                   // 16 channel phases

    float4 l0 = *(const float4*)(Lsum + (size_t)b * SS + s0);
    float4 l1 = *(const float4*)(Lsum + ((size_t)BB + b) * SS + s0);
    float rinv[4];
    rinv[0] = 1.f / (l0.x + l1.x); rinv[1] = 1.f / (l0.y + l1.y);
    rinv[2] = 1.f / (l0.z + l1.z); rinv[3] = 1.f / (l0.w + l1.w);

    const unsigned short* qb = Qbuf + (size_t)b * SS * CC;
    for (int c = coff; c < CC; c += 16) {
        const size_t po = ((size_t)b * CC + c) * SS + s0;
        ushort4 p0 = *(const ushort4*)(Opart + po);
        ushort4 p1 = *(const ushort4*)(Opart + (size_t)BB * CC * SS + po);
        float4 o;
        o.x = (b2f(p0.x) + b2f(p1.x)) * rinv[0] + b2f(qb[(size_t)(s0 + 0) * CC + c]);
        o.y = (b2f(p0.y) + b2f(p1.y)) * rinv[1] + b2f(qb[(size_t)(s0 + 1) * CC + c]);
        o.z = (b2f(p0.z) + b2f(p1.z)) * rinv[2] + b2f(qb[(size_t)(s0 + 2) * CC + c]);
        o.w = (b2f(p0.w) + b2f(p1.w)) * rinv[3] + b2f(qb[(size_t)(s0 + 3) * CC + c]);
        *(float4*)(out + po) = o;
    }
}

extern "C" void kernel_launch(void* const* d_in, const int* in_sizes, int n_in,
                              void* d_out, int out_size, void* d_ws, size_t ws_size,
                              hipStream_t stream) {
    const float* qimg = (const float*)d_in[0];
    const float* kimg = (const float*)d_in[1];
    const float* vimg = (const float*)d_in[2];
    const float* Wq   = (const float*)d_in[3];
    const float* bq   = (const float*)d_in[4];
    const float* Wk   = (const float*)d_in[5];
    const float* bk   = (const float*)d_in[6];
    float* out = (float*)d_out;

    // workspace map (~40.3 MB):
    unsigned short* Qbuf = (unsigned short*)d_ws;                    // 8 MB
    unsigned short* Kbuf = Qbuf + (size_t)BB * SS * CC;              // 8 MB
    unsigned short* Vbuf = Kbuf + (size_t)BB * SS * CC;              // 8 MB
    unsigned short* Opart = Vbuf + (size_t)BB * SS * CC;             // 16 MB bf16
    float* Lsum = (float*)(Opart + (size_t)NSPLIT * BB * CC * SS);   // 256 KB

    proj_kernel<<<dim3(SS / 64, BB, 3), 256, 0, stream>>>(
        qimg, kimg, vimg, Wq, Wk, bq, bk, Qbuf, Kbuf, Vbuf);
    attn_kernel<<<dim3(NSPLIT * BB * (SS / 128)), 256, 0, stream>>>(
        Qbuf, Kbuf, Vbuf, Opart, Lsum);
    combine_kernel<<<dim3(SS / 64, BB), 256, 0, stream>>>(Qbuf, Opart, Lsum, out);
}

// Round 6
// 194.645 us; speedup vs baseline: 1.3365x; 1.0771x over previous
//
#include <hip/hip_runtime.h>

// Shapes fixed by the reference: B=8, C=128, H=W=64 -> S=4096. All I/O fp32.
#define BB 8
#define CC 128
#define SS 4096
#define KT 64             // kv tile per iteration
#define NSPLIT 2          // KV split factor (flash-style partial softmax)
#define HKV (SS / NSPLIT) // kv tokens per block = 2048
#define SCALE 0.015625f   // 1/sqrt(H*W) = 1/64

typedef __attribute__((ext_vector_type(8))) short sh8;   // 8 bf16 (MFMA A/B frag)
typedef __attribute__((ext_vector_type(4))) float f32x4; // MFMA C/D frag

__device__ __forceinline__ float b2f(unsigned short u) {
    union { unsigned int i; float f; } x; x.i = ((unsigned int)u) << 16; return x.f;
}
__device__ __forceinline__ unsigned short f2b(float f) {  // RNE
    union { float f; unsigned int i; } x; x.f = f;
    unsigned int r = x.i + 0x7fff + ((x.i >> 16) & 1);
    return (unsigned short)(r >> 16);
}
__device__ __forceinline__ unsigned short rhu(float f) {  // round-half-up, 2 VALU
    union { float f; unsigned int i; } x; x.f = f;
    return (unsigned short)((x.i + 0x8000) >> 16);
}
// pack 2 f32 -> 2 bf16 in one dword (lo = first arg). No builtin on gfx950.
__device__ __forceinline__ unsigned int cvtpk(float lo, float hi) {
    unsigned int r;
    asm("v_cvt_pk_bf16_f32 %0, %1, %2" : "=v"(r) : "v"(lo), "v"(hi));
    return r;
}

// async 16B global->LDS DMA (lane i writes lds_base + i*16; LDS base wave-uniform)
__device__ __forceinline__ void dma16(const void* g, void* l) {
    __builtin_amdgcn_global_load_lds((const __attribute__((address_space(1))) void*)g,
                                     (__attribute__((address_space(3))) void*)l,
                                     16, 0, 0);
}

// ---------------------------------------------------------------------------
// cvt: V fp32->bf16 (layout preserved) + W/bias fp32->bf16 (one-time).
// blocks 0..511: V. blocks 512..519: Wq|Wk|bq|bk concat (33024 elems).
// (round-0 verbatim: pre-converted bf16 weights keep proj's inner loop lean)
// ---------------------------------------------------------------------------
__global__ __launch_bounds__(256) void cvt_kernel(
    const float* __restrict__ vimg,
    const float* __restrict__ Wq, const float* __restrict__ Wk,
    const float* __restrict__ bq, const float* __restrict__ bk,
    unsigned short* __restrict__ Vbuf,
    unsigned short* __restrict__ Wqb, unsigned short* __restrict__ Wkb,
    unsigned short* __restrict__ bqb, unsigned short* __restrict__ bkb)
{
    const int bx = blockIdx.x, tid = threadIdx.x;
    if (bx < 512) {
        const size_t base = (size_t)bx * 8192 + tid * 4;
        #pragma unroll
        for (int it = 0; it < 8; ++it) {
            const size_t i = base + (size_t)it * 1024;
            float4 v = *(const float4*)(vimg + i);
            ushort4 o;
            o.x = f2b(v.x); o.y = f2b(v.y); o.z = f2b(v.z); o.w = f2b(v.w);
            *(ushort4*)(Vbuf + i) = o;
        }
    } else {
        const int w = bx - 512;  // 0..7
        for (int e = w * 256 + tid; e < 33024; e += 2048) {
            float v; unsigned short* dst;
            if (e < 16384)      { v = Wq[e];         dst = Wqb + e; }
            else if (e < 32768) { v = Wk[e - 16384]; dst = Wkb + (e - 16384); }
            else if (e < 32896) { v = bq[e - 32768]; dst = bqb + (e - 32768); }
            else                { v = bk[e - 32896]; dst = bkb + (e - 32896); }
            *dst = f2b(v);
        }
    }
}

// ---------------------------------------------------------------------------
// Projection (bf16 weights) with LDS-transposed img staging + NEW coalesced
// epilogue: acc -> LDS [64 s][132 o] -> ushort4 row stores (256 B/wave-row),
// replacing 32 scalar 2 B strided stores per thread.
// outTok[b][s][o] = sum_c img[b][c][s] * W[o][c] + bias[o]
// grid=(64, 8, 2): z=0 -> Q, z=1 -> K.
// ---------------------------------------------------------------------------
__global__ __launch_bounds__(256) void proj_kernel(
    const float* __restrict__ qimg, const float* __restrict__ kimg,
    const unsigned short* __restrict__ Wqb, const unsigned short* __restrict__ Wkb,
    const unsigned short* __restrict__ bqb, const unsigned short* __restrict__ bkb,
    unsigned short* __restrict__ Qbuf, unsigned short* __restrict__ Kbuf)
{
    __shared__ float ilds[128 * 69];   // 128 chans x (64 tokens + 5 pad) = 35,328 B

    const int z = blockIdx.z;
    const float* img = (z == 0) ? qimg : kimg;
    const unsigned short* Wb = (z == 0) ? Wqb : Wkb;
    const unsigned short* bias = (z == 0) ? bqb : bkb;
    unsigned short* outTok = (z == 0) ? Qbuf : Kbuf;

    const int tid  = threadIdx.x;
    const int wave = tid >> 6;
    const int lane = tid & 63;
    const int l15  = lane & 15;
    const int quad = lane >> 4;
    const int b     = blockIdx.y;
    const int stile = blockIdx.x;

    // stage 128x64 fp32 tile, coalesced (64B contiguous per 16 lanes)
    const float* gbase = img + (size_t)b * CC * SS + stile * 64;
    #pragma unroll
    for (int i = 0; i < 8; ++i) {
        const int l = tid + 256 * i;          // 0..2047
        const int row = l >> 4, col = (l & 15) * 4;
        float4 v = *(const float4*)(gbase + (size_t)row * SS + col);
        float* d = ilds + row * 69 + col;
        d[0] = v.x; d[1] = v.y; d[2] = v.z; d[3] = v.w;
    }
    __syncthreads();

    // A-frags from LDS: A[m=l15][k=32kk+quad*8+j] = img[c=k][token]
    const int tcol = wave * 16 + l15;
    sh8 a[4];
    #pragma unroll
    for (int kk = 0; kk < 4; ++kk)
        #pragma unroll
        for (int j = 0; j < 8; ++j)
            a[kk][j] = (short)rhu(ilds[(32 * kk + quad * 8 + j) * 69 + tcol]);

    f32x4 acc[8];
    #pragma unroll
    for (int nt = 0; nt < 8; ++nt) acc[nt] = (f32x4){0.f, 0.f, 0.f, 0.f};

    #pragma unroll
    for (int nt = 0; nt < 8; ++nt) {
        const unsigned short* wp = Wb + (size_t)(16 * nt + l15) * CC + quad * 8;
        #pragma unroll
        for (int kk = 0; kk < 4; ++kk) {
            sh8 bf = *(const sh8*)(wp + 32 * kk);
            acc[nt] = __builtin_amdgcn_mfma_f32_16x16x32_bf16(a[kk], bf, acc[nt], 0, 0, 0);
        }
    }

    __syncthreads();   // all ilds A-frag reads done; safe to alias
    unsigned short* oT = (unsigned short*)ilds;   // [64 s][132 o] ushorts
    #pragma unroll
    for (int nt = 0; nt < 8; ++nt) {
        const int o = 16 * nt + l15;
        const float bv = b2f(bias[o]);
        #pragma unroll
        for (int r = 0; r < 4; ++r) {
            const int sl = wave * 16 + quad * 4 + r;
            oT[sl * 132 + o] = f2b(acc[nt][r] + bv);   // 2-way banks (free)
        }
    }
    __syncthreads();

    unsigned short* orow = outTok + ((size_t)b * SS + stile * 64) * CC;
    #pragma unroll
    for (int i = 0; i < 8; ++i) {
        const int idx = tid + 256 * i;      // 0..2047
        const int s = idx >> 5, o4 = (idx & 31) * 4;
        *(ushort4*)(orow + (size_t)s * CC + o4) = *(const ushort4*)(oT + s * 132 + o4);
    }
}

// ---------------------------------------------------------------------------
// Flash attention v4 (UNCHANGED from round 5 except partial-O destination):
// partials are interleaved INSIDE the final output buffer -- each 16 B
// float4 group-slot g holds [ushort4 half0 | ushort4 half1] at byte 16g+8h.
// combine later reads one uint4 and overwrites its own slot (race-free).
// ---------------------------------------------------------------------------
__global__ __launch_bounds__(256, 2) void attn_kernel(
    const unsigned short* __restrict__ Qbuf,  // (B,S,C) bf16 token-major
    const unsigned short* __restrict__ Kbuf,  // (B,S,C) bf16 token-major
    const unsigned short* __restrict__ Vbuf,  // (B,C,S) bf16 channel-major
    float* __restrict__ Oout,                 // (B,C,S) fp32 slots w/ packed partials
    float* __restrict__ Lsum)                 // (NSPLIT,B,S) f32 partial sums
{
    __shared__ __align__(16) unsigned char smem[65536];

    const int tid  = threadIdx.x;
    const int wave = tid >> 6;
    const int lane = tid & 63;
    const int l15  = lane & 15;
    const int quad = lane >> 4;
    const int wgid = blockIdx.x;
    const int b    = wgid & 7;          // batch == XCD (L2 holds one batch's K/V)
    const int half = (wgid >> 3) & 1;   // KV half
    const int qt   = wgid >> 4;         // 0..31, 128 queries each
    const int qbase = qt * 128 + wave * 32;
    const int tok0  = half * HKV;

    const unsigned short* kbp = Kbuf + (size_t)b * SS * CC;
    const unsigned short* vbp = Vbuf + (size_t)b * CC * SS;

    // Q frags (B operand of swapped QK)
    sh8 aq[2][4];
    #pragma unroll
    for (int m = 0; m < 2; ++m) {
        const unsigned short* qp = Qbuf + ((size_t)b * SS + qbase + m * 16 + l15) * CC + quad * 8;
        #pragma unroll
        for (int kk = 0; kk < 4; ++kk) aq[m][kk] = *(const sh8*)(qp + 32 * kk);
    }

    // DMA source offsets (bytes), constant across iterations
    int kGO[4], vGO[4];
    #pragma unroll
    for (int j = 0; j < 4; ++j) {
        const int krow = wave * 16 + j * 4 + quad;
        const int sx = (krow & 3) | ((krow >> 1) & 4);
        kGO[j] = krow * 256 + (((lane & 15) ^ sx) << 4);
        const int vrow = (wave * 4 + j) * 8 + (lane >> 3);
        vGO[j] = vrow * 8192 + (((lane & 7) ^ ((lane >> 3) & 7)) << 4);
    }

    // K read addressing: permuted row per frag n; swizzle term == l15&7 for all n
    int krb[4];
    #pragma unroll
    for (int n = 0; n < 4; ++n)
        krb[n] = (32 * (n >> 1) + 8 * (l15 >> 2) + 4 * (n & 1) + (l15 & 3)) * 256;
    const int krs = l15 & 7;

    f32x4 oacc[2][8];
    #pragma unroll
    for (int m = 0; m < 2; ++m)
        #pragma unroll
        for (int ct = 0; ct < 8; ++ct) oacc[m][ct] = (f32x4){0.f, 0.f, 0.f, 0.f};
    float lsum[2] = {0.f, 0.f};

    const char* gk0 = (const char*)kbp + (size_t)tok0 * 256;
    const char* gv0 = (const char*)vbp + (size_t)tok0 * 2;

    // prologue: stage K[0], V[0] into buffer 0
    #pragma unroll
    for (int j = 0; j < 4; ++j) {
        dma16(gk0 + kGO[j], smem + (wave * 4 + j) * 1024);
        dma16(gv0 + vGO[j], smem + 32768 + (wave * 4 + j) * 1024);
    }

    for (int it = 0; it < HKV / KT; ++it) {
        unsigned char* kb = smem + ((it & 1) << 14);
        unsigned char* vb = smem + 32768 + ((it & 1) << 14);

        // one barrier/iter: drains own DMA (vmcnt) + own LDS reads (lgkm),
        // then syncs -> K[it],V[it] resident and other buffers reusable.
        __syncthreads();

        // issue next-tile DMA into the other buffers; lands by next barrier
        if (it + 1 < HKV / KT) {
            const char* gk = gk0 + (size_t)(it + 1) * KT * 256;
            const char* gv = gv0 + (size_t)(it + 1) * KT * 2;
            unsigned char* kbn = smem + (((it + 1) & 1) << 14);
            unsigned char* vbn = smem + 32768 + (((it + 1) & 1) << 14);
            #pragma unroll
            for (int j = 0; j < 4; ++j) {
                dma16(gk + kGO[j], kbn + (wave * 4 + j) * 1024);
                dma16(gv + vGO[j], vbn + (wave * 4 + j) * 1024);
            }
        }

        // --- S^T = K Q^T with permuted K rows ---
        f32x4 sacc[2][4];
        #pragma unroll
        for (int m = 0; m < 2; ++m)
            #pragma unroll
            for (int n = 0; n < 4; ++n) sacc[m][n] = (f32x4){0.f, 0.f, 0.f, 0.f};
        __builtin_amdgcn_s_setprio(1);
        #pragma unroll
        for (int n = 0; n < 4; ++n) {
            #pragma unroll
            for (int kk = 0; kk < 4; ++kk) {
                sh8 kf = *(const sh8*)(kb + krb[n] + (((4 * kk + quad) ^ krs) << 4));
                sacc[0][n] = __builtin_amdgcn_mfma_f32_16x16x32_bf16(kf, aq[0][kk], sacc[0][n], 0, 0, 0);
                sacc[1][n] = __builtin_amdgcn_mfma_f32_16x16x32_bf16(kf, aq[1][kk], sacc[1][n], 0, 0, 0);
            }
        }
        __builtin_amdgcn_s_setprio(0);

        // --- softmax fully in-register: exp, accumulate, pack to PV A-frags ---
        union { sh8 v; unsigned int d[4]; } pa[2][2];
        #pragma unroll
        for (int m = 0; m < 2; ++m) {
            float p[4][4];
            #pragma unroll
            for (int n = 0; n < 4; ++n)
                #pragma unroll
                for (int r = 0; r < 4; ++r) {
                    p[n][r] = __expf(sacc[m][n][r] * SCALE);
                    lsum[m] += p[n][r];
                }
            #pragma unroll
            for (int kp = 0; kp < 2; ++kp) {
                pa[m][kp].d[0] = cvtpk(p[2 * kp][0],     p[2 * kp][1]);
                pa[m][kp].d[1] = cvtpk(p[2 * kp][2],     p[2 * kp][3]);
                pa[m][kp].d[2] = cvtpk(p[2 * kp + 1][0], p[2 * kp + 1][1]);
                pa[m][kp].d[3] = cvtpk(p[2 * kp + 1][2], p[2 * kp + 1][3]);
            }
        }

        // --- PV: P from registers, V from LDS (8 frag reads per kp) ---
        __builtin_amdgcn_s_setprio(1);
        #pragma unroll
        for (int kp = 0; kp < 2; ++kp) {
            #pragma unroll
            for (int ct = 0; ct < 8; ++ct) {
                sh8 bv = *(const sh8*)(vb + (16 * ct + l15) * 128
                                          + (((kp * 4 + quad) ^ (l15 & 7)) << 4));
                oacc[0][ct] = __builtin_amdgcn_mfma_f32_16x16x32_bf16(pa[0][kp].v, bv, oacc[0][ct], 0, 0, 0);
                oacc[1][ct] = __builtin_amdgcn_mfma_f32_16x16x32_bf16(pa[1][kp].v, bv, oacc[1][ct], 0, 0, 0);
            }
        }
        __builtin_amdgcn_s_setprio(0);
    }

    // --- total row-sum: add across the 4 quads holding the same query ---
    #pragma unroll
    for (int m = 0; m < 2; ++m) {
        lsum[m] += __shfl_xor(lsum[m], 16, 64);
        lsum[m] += __shfl_xor(lsum[m], 32, 64);
    }
    if (quad == 0) {
        float* lp = Lsum + ((size_t)half * BB + b) * SS + qbase;
        lp[l15]      = lsum[0];
        lp[16 + l15] = lsum[1];
    }

    __syncthreads();   // all K/V-buffer reads done before aliasing smem

    // --- epilogue: unnormalized O -> bf16, LDS transpose, packed-slot store ---
    unsigned short* oT = (unsigned short*)smem;   // [128 c][136 pad] ushorts
    #pragma unroll
    for (int m = 0; m < 2; ++m)
        #pragma unroll
        for (int ct = 0; ct < 8; ++ct) {
            const int c  = 16 * ct + l15;
            const int q0 = wave * 32 + m * 16 + quad * 4;
            ushort4 o;
            o.x = rhu(oacc[m][ct][0]); o.y = rhu(oacc[m][ct][1]);
            o.z = rhu(oacc[m][ct][2]); o.w = rhu(oacc[m][ct][3]);
            *(ushort4*)(oT + c * 136 + q0) = o;
        }
    __syncthreads();

    char* ob = (char*)Oout;
    #pragma unroll
    for (int i = 0; i < 16; ++i) {
        const int idx = tid + 256 * i;        // 0..4095
        const int c = idx >> 5, q4 = (idx & 31) * 4;
        const size_t fo = ((size_t)b * CC + c) * SS + qt * 128 + q4;  // %4 == 0
        *(ushort4*)(ob + fo * 4 + 8 * half) = *(const ushort4*)(oT + c * 136 + q4);
    }
}

// ---------------------------------------------------------------------------
// combine: out[b][c][s] = (O0+O1)/(L0+L1) + resid(Qbuf[b][s][c]).
// Partials read as one uint4 from the slot this thread will overwrite.
// Residual staged through LDS (coalesced ushort4 global reads), killing the
// 32 scattered 2 B global loads per thread. grid (64,8), 256 thr.
// ---------------------------------------------------------------------------
__global__ __launch_bounds__(256) void combine_kernel(
    const unsigned short* __restrict__ Qbuf,
    const float* __restrict__ Lsum,
    float* __restrict__ out)    // slots currently hold packed partials
{
    __shared__ unsigned short rS[64][132];   // 16,896 B
    const int b = blockIdx.y, st = blockIdx.x, tid = threadIdx.x;

    // stage resid slab (64 tokens x 128 chans), coalesced
    const unsigned short* qb = Qbuf + ((size_t)b * SS + st * 64) * CC;
    #pragma unroll
    for (int i = 0; i < 8; ++i) {
        const int idx = tid + 256 * i;       // 0..2047
        const int s = idx >> 5, c4 = (idx & 31) * 4;
        *(ushort4*)(&rS[s][c4]) = *(const ushort4*)(qb + (size_t)s * CC + c4);
    }
    __syncthreads();

    const int s0l = (tid & 15) * 4;          // local 4-token group
    const int s0  = st * 64 + s0l;
    const int coff = tid >> 4;

    float4 l0 = *(const float4*)(Lsum + (size_t)b * SS + s0);
    float4 l1 = *(const float4*)(Lsum + ((size_t)BB + b) * SS + s0);
    float rinv[4];
    rinv[0] = 1.f / (l0.x + l1.x); rinv[1] = 1.f / (l0.y + l1.y);
    rinv[2] = 1.f / (l0.z + l1.z); rinv[3] = 1.f / (l0.w + l1.w);

    for (int c = coff; c < CC; c += 16) {
        const size_t po = ((size_t)b * CC + c) * SS + s0;   // float idx, %4==0
        uint4 u = *(const uint4*)((const char*)out + po * 4);
        float4 o;
        o.x = (b2f((unsigned short)(u.x & 0xffff)) + b2f((unsigned short)(u.z & 0xffff))) * rinv[0]
              + b2f(rS[s0l + 0][c]);
        o.y = (b2f((unsigned short)(u.x >> 16))    + b2f((unsigned short)(u.z >> 16)))    * rinv[1]
              + b2f(rS[s0l + 1][c]);
        o.z = (b2f((unsigned short)(u.y & 0xffff)) + b2f((unsigned short)(u.w & 0xffff))) * rinv[2]
              + b2f(rS[s0l + 2][c]);
        o.w = (b2f((unsigned short)(u.y >> 16))    + b2f((unsigned short)(u.w >> 16)))    * rinv[3]
              + b2f(rS[s0l + 3][c]);
        *(float4*)(out + po) = o;
    }
}

extern "C" void kernel_launch(void* const* d_in, const int* in_sizes, int n_in,
                              void* d_out, int out_size, void* d_ws, size_t ws_size,
                              hipStream_t stream) {
    const float* qimg = (const float*)d_in[0];
    const float* kimg = (const float*)d_in[1];
    const float* vimg = (const float*)d_in[2];
    const float* Wq   = (const float*)d_in[3];
    const float* bq   = (const float*)d_in[4];
    const float* Wk   = (const float*)d_in[5];
    const float* bk   = (const float*)d_in[6];
    float* out = (float*)d_out;

    // workspace map (~24.3 MB): partials live inside d_out (packed slots)
    unsigned short* Qbuf = (unsigned short*)d_ws;                    // 8 MB
    unsigned short* Kbuf = Qbuf + (size_t)BB * SS * CC;              // 8 MB
    unsigned short* Vbuf = Kbuf + (size_t)BB * SS * CC;              // 8 MB
    unsigned short* Wqb  = Vbuf + (size_t)BB * SS * CC;              // 32 KB
    unsigned short* Wkb  = Wqb + CC * CC;                            // 32 KB
    unsigned short* bqb  = Wkb + CC * CC;
    unsigned short* bkb  = bqb + CC;
    float* Lsum = (float*)(bkb + CC);                                // 256 KB

    cvt_kernel<<<dim3(520), 256, 0, stream>>>(vimg, Wq, Wk, bq, bk,
                                              Vbuf, Wqb, Wkb, bqb, bkb);
    proj_kernel<<<dim3(SS / 64, BB, 2), 256, 0, stream>>>(
        qimg, kimg, Wqb, Wkb, bqb, bkb, Qbuf, Kbuf);
    attn_kernel<<<dim3(NSPLIT * BB * (SS / 128)), 256, 0, stream>>>(
        Qbuf, Kbuf, Vbuf, out, Lsum);
    combine_kernel<<<dim3(SS / 64, BB), 256, 0, stream>>>(Qbuf, Lsum, out);
}